// Round 1
// baseline (519.503 us; speedup 1.0000x reference)
//
#include <hip/hip_runtime.h>

#define DEV __device__ __forceinline__

typedef __attribute__((ext_vector_type(4))) float f32x4;
typedef __attribute__((ext_vector_type(4))) float float4v;
typedef __attribute__((ext_vector_type(4))) unsigned short u16x4;
typedef __attribute__((ext_vector_type(8))) __bf16 bf16x8;

constexpr int NB = 16;     // batches
constexpr int SL = 2048;   // sequence length
constexpr int EM = 1024;   // embedding dim
constexpr int DKD = 128;   // head dim

DEV unsigned short f2bf(float f) {           // fp32 -> bf16 RNE
  unsigned int u = __float_as_uint(f);
  u += 0x7FFFu + ((u >> 16) & 1u);
  return (unsigned short)(u >> 16);
}

union Frag { u16x4 h[2]; bf16x8 v; };

DEV f32x4 mfma16(bf16x8 a, bf16x8 b, f32x4 c) {
  return __builtin_amdgcn_mfma_f32_16x16x32_bf16(a, b, c, 0, 0, 0);
}

// ---------------------------------------------------------------------------
// Projection Q,K = context @ {Wq,Wk}.  Q gets len-mask + log2e/sqrt(dk) scale.
// 256 thr = 4 waves; wave computes 16 rows x 128 cols. grid.x = 32768/64.
// ---------------------------------------------------------------------------
__global__ __launch_bounds__(256, 2) void proj_qk_kernel(
    const float* __restrict__ ctx, const float* __restrict__ Wq,
    const float* __restrict__ Wk, const int* __restrict__ lens,
    unsigned short* __restrict__ Qo, unsigned short* __restrict__ Ko)
{
  __shared__ unsigned short WTq[128 * 36];   // W chunk transposed [n][k(32)+pad]
  __shared__ unsigned short WTk[128 * 36];
  const int tid = threadIdx.x;
  const int wave = tid >> 6, lane = tid & 63;
  const int quad = lane >> 4, mm = lane & 15;
  const int rb = blockIdx.x * 64 + wave * 16;

  f32x4 accQ[8], accK[8];
  #pragma unroll
  for (int i = 0; i < 8; ++i) { accQ[i] = f32x4{0.f,0.f,0.f,0.f}; accK[i] = f32x4{0.f,0.f,0.f,0.f}; }
  const float* arow = ctx + (size_t)(rb + mm) * EM;

  #pragma unroll 1
  for (int kc = 0; kc < EM / 32; ++kc) {
    __syncthreads();
    // stage 32x128 chunk of each weight, transposed, fp32->bf16
    #pragma unroll
    for (int it = 0; it < 4; ++it) {
      int idx = it * 256 + tid;              // [0,1024) float4 units
      int k = idx >> 5;                      // 0..31
      int n4 = (idx & 31) * 4;               // 0..124
      float4v q4 = *(const float4v*)(Wq + (size_t)(kc * 32 + k) * DKD + n4);
      float4v k4 = *(const float4v*)(Wk + (size_t)(kc * 32 + k) * DKD + n4);
      #pragma unroll
      for (int j = 0; j < 4; ++j) {
        WTq[(n4 + j) * 36 + k] = f2bf(q4[j]);
        WTk[(n4 + j) * 36 + k] = f2bf(k4[j]);
      }
    }
    __syncthreads();
    // A fragment: row = rb+mm, k = kc*32 + quad*8 + j
    Frag fa;
    {
      const float* ap = arow + kc * 32 + quad * 8;
      float4v a0 = *(const float4v*)ap;
      float4v a1 = *(const float4v*)(ap + 4);
      fa.h[0] = u16x4{ f2bf(a0[0]), f2bf(a0[1]), f2bf(a0[2]), f2bf(a0[3]) };
      fa.h[1] = u16x4{ f2bf(a1[0]), f2bf(a1[1]), f2bf(a1[2]), f2bf(a1[3]) };
    }
    #pragma unroll
    for (int nt = 0; nt < 8; ++nt) {
      Frag fq, fk;
      const unsigned short* bq = &WTq[(nt * 16 + mm) * 36 + quad * 8];
      const unsigned short* bk = &WTk[(nt * 16 + mm) * 36 + quad * 8];
      fq.h[0] = *(const u16x4*)bq;       fq.h[1] = *(const u16x4*)(bq + 4);
      fk.h[0] = *(const u16x4*)bk;       fk.h[1] = *(const u16x4*)(bk + 4);
      accQ[nt] = mfma16(fa.v, fq.v, accQ[nt]);
      accK[nt] = mfma16(fa.v, fk.v, accK[nt]);
    }
  }
  // epilogue: C/D layout row = quad*4+reg, col = mm
  const int bidx = rb >> 11;
  const int len = lens[bidx];
  const float SCALE = 1.4426950408889634f * 0.08838834764831845f; // log2e/sqrt(128)
  #pragma unroll
  for (int reg = 0; reg < 4; ++reg) {
    int row = rb + quad * 4 + reg;
    float qs = ((row & (SL - 1)) < len) ? SCALE : 0.f;   // Q len-mask (+scale)
    size_t base = (size_t)row * DKD + mm;
    #pragma unroll
    for (int nt = 0; nt < 8; ++nt) {
      Qo[base + nt * 16] = f2bf(accQ[nt][reg] * qs);
      Ko[base + nt * 16] = f2bf(accK[nt][reg]);
    }
  }
}

// ---------------------------------------------------------------------------
// Projection V = x @ Wv, stored TRANSPOSED as Vt[b][d][i] (bf16) for the
// PV B-fragment (k-contiguous over keys).
// ---------------------------------------------------------------------------
__global__ __launch_bounds__(256, 2) void proj_v_kernel(
    const float* __restrict__ x, const float* __restrict__ Wv,
    unsigned short* __restrict__ Vo)
{
  __shared__ unsigned short WT[128 * 36];
  const int tid = threadIdx.x;
  const int wave = tid >> 6, lane = tid & 63;
  const int quad = lane >> 4, mm = lane & 15;
  const int rb = blockIdx.x * 64 + wave * 16;

  f32x4 acc[8];
  #pragma unroll
  for (int i = 0; i < 8; ++i) acc[i] = f32x4{0.f,0.f,0.f,0.f};
  const float* arow = x + (size_t)(rb + mm) * EM;

  #pragma unroll 1
  for (int kc = 0; kc < EM / 32; ++kc) {
    __syncthreads();
    #pragma unroll
    for (int it = 0; it < 4; ++it) {
      int idx = it * 256 + tid;
      int k = idx >> 5;
      int n4 = (idx & 31) * 4;
      float4v v4 = *(const float4v*)(Wv + (size_t)(kc * 32 + k) * DKD + n4);
      #pragma unroll
      for (int j = 0; j < 4; ++j) WT[(n4 + j) * 36 + k] = f2bf(v4[j]);
    }
    __syncthreads();
    Frag fa;
    {
      const float* ap = arow + kc * 32 + quad * 8;
      float4v a0 = *(const float4v*)ap;
      float4v a1 = *(const float4v*)(ap + 4);
      fa.h[0] = u16x4{ f2bf(a0[0]), f2bf(a0[1]), f2bf(a0[2]), f2bf(a0[3]) };
      fa.h[1] = u16x4{ f2bf(a1[0]), f2bf(a1[1]), f2bf(a1[2]), f2bf(a1[3]) };
    }
    #pragma unroll
    for (int nt = 0; nt < 8; ++nt) {
      Frag fv;
      const unsigned short* bp = &WT[(nt * 16 + mm) * 36 + quad * 8];
      fv.h[0] = *(const u16x4*)bp;  fv.h[1] = *(const u16x4*)(bp + 4);
      acc[nt] = mfma16(fa.v, fv.v, acc[nt]);
    }
  }
  // transposed epilogue: Vt[b][d][i], 4 consecutive i (reg) packed per store
  const int bidx = rb >> 11;
  const int i0 = (rb & (SL - 1)) + quad * 4;
  #pragma unroll
  for (int nt = 0; nt < 8; ++nt) {
    int d = nt * 16 + mm;
    u16x4 pk = u16x4{ f2bf(acc[nt][0]), f2bf(acc[nt][1]),
                      f2bf(acc[nt][2]), f2bf(acc[nt][3]) };
    *(u16x4*)(Vo + (size_t)bidx * DKD * SL + (size_t)d * SL + i0) = pk;
  }
}

// ---------------------------------------------------------------------------
// Flash attention: wg = 64 query rows of one batch (4 waves x 16 rows),
// iterate 32-key blocks staged in LDS; online softmax; P via LDS transpose.
// ---------------------------------------------------------------------------
__global__ __launch_bounds__(256, 2) void attn_kernel(
    const unsigned short* __restrict__ Qw, const unsigned short* __restrict__ Kw,
    const unsigned short* __restrict__ Vw, const int* __restrict__ lens,
    float* __restrict__ out)
{
  __shared__ unsigned short Ks[32 * 132];      // K block [j][d+pad4]
  __shared__ unsigned short Vs[128 * 36];      // Vt block [d][j+pad4]
  __shared__ unsigned short Ps[4][16 * 40];    // per-wave P [q][j+pad8]
  const int tid = threadIdx.x;
  const int wave = tid >> 6, lane = tid & 63;
  const int quad = lane >> 4, mm = lane & 15;
  const int b = blockIdx.y;
  const int qb = blockIdx.x * 64;
  const int len = lens[b];
  const int kend = min(qb + 64, len);
  const int nblk = (kend + 31) >> 5;
  const int irow0 = qb + wave * 16 + quad * 4;   // + reg

  Frag aQ[4];
  {
    const unsigned short* qbase =
        Qw + (size_t)(b * SL + qb + wave * 16 + mm) * DKD + quad * 8;
    #pragma unroll
    for (int c = 0; c < 4; ++c) {
      aQ[c].h[0] = *(const u16x4*)(qbase + c * 32);
      aQ[c].h[1] = *(const u16x4*)(qbase + c * 32 + 4);
    }
  }
  float mr[4], lr[4];
  #pragma unroll
  for (int r = 0; r < 4; ++r) { mr[r] = -__builtin_inff(); lr[r] = 0.f; }
  f32x4 acc[8];
  #pragma unroll
  for (int i = 0; i < 8; ++i) acc[i] = f32x4{0.f,0.f,0.f,0.f};

  #pragma unroll 1
  for (int blk = 0; blk < nblk; ++blk) {
    const int kb = blk * 32;
    __syncthreads();
    #pragma unroll
    for (int it = 0; it < 2; ++it) {
      int idx = it * 256 + tid;
      { // K: 32 rows x 128 d  (512 8-elem chunks)
        int ds = idx & 15, j = idx >> 4;
        const unsigned short* g = Kw + (size_t)(b * SL + kb + j) * DKD + ds * 8;
        u16x4 h0 = *(const u16x4*)g;
        u16x4 h1 = *(const u16x4*)(g + 4);
        *(u16x4*)&Ks[j * 132 + ds * 8] = h0;
        *(u16x4*)&Ks[j * 132 + ds * 8 + 4] = h1;
      }
      { // Vt: 128 d-rows x 32 keys
        int js = idx & 3, d = idx >> 2;
        const unsigned short* g =
            Vw + (size_t)b * DKD * SL + (size_t)d * SL + kb + js * 8;
        u16x4 h0 = *(const u16x4*)g;
        u16x4 h1 = *(const u16x4*)(g + 4);
        *(u16x4*)&Vs[d * 36 + js * 8] = h0;
        *(u16x4*)&Vs[d * 36 + js * 8 + 4] = h1;
      }
    }
    __syncthreads();

    // S = Q K^T for two 16-key tiles
    f32x4 s[2];
    #pragma unroll
    for (int nt = 0; nt < 2; ++nt) {
      f32x4 c = f32x4{0.f,0.f,0.f,0.f};
      const unsigned short* kr = &Ks[(nt * 16 + mm) * 132 + quad * 8];
      #pragma unroll
      for (int cc = 0; cc < 4; ++cc) {
        Frag fb;
        fb.h[0] = *(const u16x4*)(kr + cc * 32);
        fb.h[1] = *(const u16x4*)(kr + cc * 32 + 4);
        c = mfma16(aQ[cc].v, fb.v, c);
      }
      s[nt] = c;
    }

    // online softmax (rows = quad*4+reg, cols = mm across the quad's 16 lanes)
    float alpha[4];
    #pragma unroll
    for (int reg = 0; reg < 4; ++reg) {
      const int jl = min(irow0 + reg + 1, len);   // keys j < jl are valid
      float s0 = (kb + mm      < jl) ? s[0][reg] : -__builtin_inff();
      float s1 = (kb + 16 + mm < jl) ? s[1][reg] : -__builtin_inff();
      float mx = fmaxf(s0, s1);
      #pragma unroll
      for (int xm = 1; xm < 16; xm <<= 1) mx = fmaxf(mx, __shfl_xor(mx, xm));
      const float mn = fmaxf(mr[reg], mx);
      alpha[reg] = __builtin_amdgcn_exp2f(mr[reg] - mn);
      const float p0 = __builtin_amdgcn_exp2f(s0 - mn);
      const float p1 = __builtin_amdgcn_exp2f(s1 - mn);
      float sm = p0 + p1;
      #pragma unroll
      for (int xm = 1; xm < 16; xm <<= 1) sm += __shfl_xor(sm, xm);
      lr[reg] = lr[reg] * alpha[reg] + sm;
      mr[reg] = mn;
      Ps[wave][(quad * 4 + reg) * 40 + mm]      = f2bf(p0);
      Ps[wave][(quad * 4 + reg) * 40 + 16 + mm] = f2bf(p1);
    }
    #pragma unroll
    for (int nt = 0; nt < 8; ++nt) {
      f32x4 a = acc[nt];
      a[0] *= alpha[0]; a[1] *= alpha[1]; a[2] *= alpha[2]; a[3] *= alpha[3];
      acc[nt] = a;
    }
    // wave-local fence: P writes -> P reads (cross-lane, same wave)
    __asm__ volatile("s_waitcnt lgkmcnt(0)" ::: "memory");
    Frag aP;
    aP.h[0] = *(const u16x4*)&Ps[wave][mm * 40 + quad * 8];
    aP.h[1] = *(const u16x4*)&Ps[wave][mm * 40 + quad * 8 + 4];
    #pragma unroll
    for (int nt = 0; nt < 8; ++nt) {
      Frag fv;
      const unsigned short* vr = &Vs[(nt * 16 + mm) * 36 + quad * 8];
      fv.h[0] = *(const u16x4*)vr;
      fv.h[1] = *(const u16x4*)(vr + 4);
      acc[nt] = mfma16(aP.v, fv.v, acc[nt]);
    }
  }

  #pragma unroll
  for (int reg = 0; reg < 4; ++reg) {
    const float rl = 1.0f / lr[reg];
    const size_t base = ((size_t)b * SL + irow0 + reg) * DKD + mm;
    #pragma unroll
    for (int nt = 0; nt < 8; ++nt)
      out[base + nt * 16] = acc[nt][reg] * rl;
  }
}

// ---------------------------------------------------------------------------
extern "C" void kernel_launch(void* const* d_in, const int* in_sizes, int n_in,
                              void* d_out, int out_size, void* d_ws, size_t ws_size,
                              hipStream_t stream) {
  const float* x    = (const float*)d_in[0];
  const float* ctx  = (const float*)d_in[1];
  const int*   lens = (const int*)d_in[2];
  const float* Wq   = (const float*)d_in[3];
  const float* Wk   = (const float*)d_in[4];
  const float* Wv   = (const float*)d_in[5];
  float* out = (float*)d_out;

  const size_t QKV = (size_t)NB * SL * DKD * sizeof(unsigned short); // 8 MiB each
  if (ws_size < 3 * QKV) return;  // insufficient scratch -> fail loudly
  unsigned short* Qws = (unsigned short*)d_ws;
  unsigned short* Kws = (unsigned short*)((char*)d_ws + QKV);
  unsigned short* Vws = (unsigned short*)((char*)d_ws + 2 * QKV);

  const int M = NB * SL;                 // 32768 rows
  proj_qk_kernel<<<dim3(M / 64), 256, 0, stream>>>(ctx, Wq, Wk, lens, Qws, Kws);
  proj_v_kernel <<<dim3(M / 64), 256, 0, stream>>>(x, Wv, Vws);
  attn_kernel   <<<dim3(SL / 64, NB), 256, 0, stream>>>(Qws, Kws, Vws, lens, out);
}

// Round 2
// 451.780 us; speedup vs baseline: 1.1499x; 1.1499x over previous
//
#include <hip/hip_runtime.h>

#define DEV __device__ __forceinline__

typedef __attribute__((ext_vector_type(4))) float f32x4;
typedef __attribute__((ext_vector_type(4))) unsigned short u16x4;
typedef __attribute__((ext_vector_type(8))) __bf16 bf16x8;

constexpr int NB = 16, SL = 2048, EM = 1024, DKD = 128;

DEV unsigned short f2bf(float f) {           // fp32 -> bf16 RNE
  unsigned int u = __float_as_uint(f);
  u += 0x7FFFu + ((u >> 16) & 1u);
  return (unsigned short)(u >> 16);
}

DEV f32x4 mfma16(bf16x8 a, bf16x8 b, f32x4 c) {
  return __builtin_amdgcn_mfma_f32_16x16x32_bf16(a, b, c, 0, 0, 0);
}

// async global->LDS DMA, 16B per lane; lds dst = wave-uniform base + lane*16
DEV void dma16(const void* g, void* l) {
  __builtin_amdgcn_global_load_lds(
      (const __attribute__((address_space(1))) unsigned int*)g,
      (__attribute__((address_space(3))) unsigned int*)l, 16, 0, 0);
}

DEV bf16x8 cvt8(f32x4 a, f32x4 b) {
  bf16x8 r;
  r[0] = (__bf16)a[0]; r[1] = (__bf16)a[1]; r[2] = (__bf16)a[2]; r[3] = (__bf16)a[3];
  r[4] = (__bf16)b[0]; r[5] = (__bf16)b[1]; r[6] = (__bf16)b[2]; r[7] = (__bf16)b[3];
  return r;
}

// ---------------------------------------------------------------------------
// prep_w: Wq/Wk/Wv fp32 [1024][128] -> bf16, tiled+swizzled, DMA-ready.
// Chunk t = ((m*16 + kc)*128 + n)*8 + p holds W_m[k = kc*64 + (p^(n&7))*8 + e][n].
// ---------------------------------------------------------------------------
__global__ __launch_bounds__(256) void prep_w(
    const float* __restrict__ Wq, const float* __restrict__ Wk,
    const float* __restrict__ Wv, unsigned short* __restrict__ Wt)
{
  const int t = blockIdx.x * 256 + threadIdx.x;    // 49152 chunks
  const int p = t & 7, n = (t >> 3) & 127, kc = (t >> 10) & 15, m = t >> 14;
  const float* W = (m == 0) ? Wq : ((m == 1) ? Wk : Wv);
  const int c = p ^ (n & 7);
  const int k0 = kc * 64 + c * 8;
  unsigned short v[8];
  #pragma unroll
  for (int e = 0; e < 8; ++e) v[e] = f2bf(W[(size_t)(k0 + e) * DKD + n]);
  u16x4 lo = u16x4{v[0], v[1], v[2], v[3]};
  u16x4 hi = u16x4{v[4], v[5], v[6], v[7]};
  *(u16x4*)(Wt + (size_t)t * 8)     = lo;
  *(u16x4*)(Wt + (size_t)t * 8 + 4) = hi;
}

// ---------------------------------------------------------------------------
// proj_qk: Q,K = ctx @ {Wq,Wk}.  M-tile 64 (grid 512), N = 256 (Q|K).
// Wave w owns coltiles w*4..w*4+3 and all 4 rowtiles (4x4 accs).
// Ws staged by DMA from pre-swizzled Wt; A direct global fp32 + in-reg cvt.
// Q written plain (len-masked, pre-scaled); K written swizzled for attn DMA.
// ---------------------------------------------------------------------------
__global__ __launch_bounds__(256, 2) void proj_qk(
    const float* __restrict__ ctx, const unsigned short* __restrict__ Wt,
    const int* __restrict__ lens, unsigned short* __restrict__ Qo,
    unsigned short* __restrict__ Kz)
{
  __shared__ unsigned short Ws[256 * 64];   // [n(Q:0-127,K:128-255)][8 chunks x 8]
  const int tid = threadIdx.x;
  const int wave = tid >> 6, lane = tid & 63;
  const int quad = lane >> 4, mm = lane & 15;
  const int rb = blockIdx.x * 64;

  f32x4 acc[4][4];                          // [rowtile][local coltile]
  #pragma unroll
  for (int i = 0; i < 4; ++i)
    #pragma unroll
    for (int j = 0; j < 4; ++j) acc[i][j] = f32x4{0.f, 0.f, 0.f, 0.f};

  #pragma unroll 1
  for (int kc = 0; kc < 16; ++kc) {
    __syncthreads();
    // A loads (issued first so cvt can start before DMA drains)
    f32x4 Av[4][2][2];
    #pragma unroll
    for (int rt = 0; rt < 4; ++rt)
      #pragma unroll
      for (int ks = 0; ks < 2; ++ks) {
        const float* ap = ctx + (size_t)(rb + rt * 16 + mm) * EM + kc * 64 + ks * 32 + quad * 8;
        Av[rt][ks][0] = *(const f32x4*)ap;
        Av[rt][ks][1] = *(const f32x4*)(ap + 4);
      }
    // DMA Wq+Wk chunk (32 KB, 8 issues)
    #pragma unroll
    for (int it = 0; it < 8; ++it) {
      int s = it * 256 + tid;
      int mtx = s >> 10, sl = s & 1023;
      dma16(Wt + ((size_t)mtx * 16384 + kc * 1024 + sl) * 8,
            (char*)Ws + (it * 256 + wave * 64) * 16);
    }
    bf16x8 af[4][2];
    #pragma unroll
    for (int rt = 0; rt < 4; ++rt)
      #pragma unroll
      for (int ks = 0; ks < 2; ++ks) af[rt][ks] = cvt8(Av[rt][ks][0], Av[rt][ks][1]);
    __syncthreads();
    #pragma unroll
    for (int lo = 0; lo < 4; ++lo) {
      const int nrow = (wave * 4 + lo) * 16 + mm;
      #pragma unroll
      for (int ks = 0; ks < 2; ++ks) {
        const int pp = (ks * 4 + quad) ^ (mm & 7);
        bf16x8 bf = *(const bf16x8*)(Ws + nrow * 64 + pp * 8);
        #pragma unroll
        for (int rt = 0; rt < 4; ++rt)
          acc[rt][lo] = mfma16(af[rt][ks], bf, acc[rt][lo]);
      }
    }
  }
  const int len = lens[blockIdx.x >> 5];
  const float SCALE = 1.4426950408889634f * 0.08838834764831845f; // log2e/sqrt(128)
  #pragma unroll
  for (int rt = 0; rt < 4; ++rt)
    #pragma unroll
    for (int lo = 0; lo < 4; ++lo) {
      const int ctg = wave * 4 + lo;
      #pragma unroll
      for (int reg = 0; reg < 4; ++reg) {
        const int row = rb + rt * 16 + quad * 4 + reg;
        const int j = row & (SL - 1);
        const float val = acc[rt][lo][reg];
        if (ctg < 8) {
          const int d = ctg * 16 + mm;
          Qo[(size_t)row * DKD + d] = f2bf(val * ((j < len) ? SCALE : 0.f));
        } else {
          const int d = (ctg - 8) * 16 + mm;
          Kz[(size_t)row * DKD + (((d >> 3) ^ (j & 15)) * 8) + (d & 7)] = f2bf(val);
        }
      }
    }
}

// ---------------------------------------------------------------------------
// proj_v: V = x @ Wv, written transposed+window-swizzled: Vz[b][d][j-windows].
// ---------------------------------------------------------------------------
__global__ __launch_bounds__(256, 2) void proj_v(
    const float* __restrict__ x, const unsigned short* __restrict__ Wt,
    unsigned short* __restrict__ Vz)
{
  __shared__ unsigned short Ws[128 * 64];
  const int tid = threadIdx.x;
  const int wave = tid >> 6, lane = tid & 63;
  const int quad = lane >> 4, mm = lane & 15;
  const int rb = blockIdx.x * 64;

  f32x4 acc[4][2];
  #pragma unroll
  for (int i = 0; i < 4; ++i) { acc[i][0] = f32x4{0.f,0.f,0.f,0.f}; acc[i][1] = f32x4{0.f,0.f,0.f,0.f}; }

  #pragma unroll 1
  for (int kc = 0; kc < 16; ++kc) {
    __syncthreads();
    f32x4 Av[4][2][2];
    #pragma unroll
    for (int rt = 0; rt < 4; ++rt)
      #pragma unroll
      for (int ks = 0; ks < 2; ++ks) {
        const float* ap = x + (size_t)(rb + rt * 16 + mm) * EM + kc * 64 + ks * 32 + quad * 8;
        Av[rt][ks][0] = *(const f32x4*)ap;
        Av[rt][ks][1] = *(const f32x4*)(ap + 4);
      }
    #pragma unroll
    for (int it = 0; it < 4; ++it) {
      int s = it * 256 + tid;
      dma16(Wt + ((size_t)2 * 16384 + kc * 1024 + s) * 8,
            (char*)Ws + (it * 256 + wave * 64) * 16);
    }
    bf16x8 af[4][2];
    #pragma unroll
    for (int rt = 0; rt < 4; ++rt)
      #pragma unroll
      for (int ks = 0; ks < 2; ++ks) af[rt][ks] = cvt8(Av[rt][ks][0], Av[rt][ks][1]);
    __syncthreads();
    #pragma unroll
    for (int lo = 0; lo < 2; ++lo) {
      const int nrow = (wave * 2 + lo) * 16 + mm;
      #pragma unroll
      for (int ks = 0; ks < 2; ++ks) {
        const int pp = (ks * 4 + quad) ^ (mm & 7);
        bf16x8 bf = *(const bf16x8*)(Ws + nrow * 64 + pp * 8);
        #pragma unroll
        for (int rt = 0; rt < 4; ++rt)
          acc[rt][lo] = mfma16(af[rt][ks], bf, acc[rt][lo]);
      }
    }
  }
  #pragma unroll
  for (int rt = 0; rt < 4; ++rt)
    #pragma unroll
    for (int lo = 0; lo < 2; ++lo) {
      const int d = (wave * 2 + lo) * 16 + mm;
      const int row0 = rb + rt * 16 + quad * 4;
      const int b = row0 >> 11, j0 = row0 & (SL - 1);
      u16x4 pk = u16x4{ f2bf(acc[rt][lo][0]), f2bf(acc[rt][lo][1]),
                        f2bf(acc[rt][lo][2]), f2bf(acc[rt][lo][3]) };
      size_t off = (size_t)b * DKD * SL + (size_t)d * SL + (j0 & ~63)
                 + ((((j0 >> 3) & 7) ^ (d & 7)) * 8) + (j0 & 7);
      *(u16x4*)(Vz + off) = pk;
    }
}

// ---------------------------------------------------------------------------
// attn: flash attention, 64 q-rows/block (4 waves x 16), 64-key blocks
// DMA-staged from pre-swizzled Kz/Vz; online softmax; P via per-wave LDS.
// ---------------------------------------------------------------------------
__global__ __launch_bounds__(256, 2) void attn(
    const unsigned short* __restrict__ Qw, const unsigned short* __restrict__ Kz,
    const unsigned short* __restrict__ Vz, const int* __restrict__ lens,
    float* __restrict__ out)
{
  __shared__ unsigned short Ks[64 * 128];    // [j][16 chunks x 8], swz c^(j&15)
  __shared__ unsigned short Vs[128 * 64];    // [d][8 chunks x 8],  swz c^(d&7)
  __shared__ unsigned short Ps[4][16 * 72];  // per-wave P [q][j+pad8]
  const int tid = threadIdx.x;
  const int wave = tid >> 6, lane = tid & 63;
  const int quad = lane >> 4, mm = lane & 15;
  const int b = blockIdx.y;
  const int qb = ((int)gridDim.x - 1 - (int)blockIdx.x) * 64;  // heavy blocks first
  const int len = lens[b];
  const int kend = min(qb + 64, len);
  const int nblk = (kend + 63) >> 6;
  const int irow0 = qb + wave * 16 + quad * 4;

  bf16x8 aQ[4];
  {
    const unsigned short* qbase =
        Qw + (size_t)(b * SL + qb + wave * 16 + mm) * DKD + quad * 8;
    #pragma unroll
    for (int cc = 0; cc < 4; ++cc) aQ[cc] = *(const bf16x8*)(qbase + cc * 32);
  }
  float mr[4], lr[4];
  #pragma unroll
  for (int r = 0; r < 4; ++r) { mr[r] = -__builtin_inff(); lr[r] = 0.f; }
  f32x4 acc[8];
  #pragma unroll
  for (int i = 0; i < 8; ++i) acc[i] = f32x4{0.f,0.f,0.f,0.f};

  #pragma unroll 1
  for (int blk = 0; blk < nblk; ++blk) {
    const int kb = blk * 64;
    __syncthreads();
    #pragma unroll
    for (int it = 0; it < 4; ++it) {   // K tile: 16 KB contiguous
      int s = it * 256 + tid;
      dma16(Kz + (size_t)(b * SL + kb) * DKD + (size_t)s * 8,
            (char*)Ks + (it * 256 + wave * 64) * 16);
    }
    #pragma unroll
    for (int it = 0; it < 4; ++it) {   // V tile: per-row window reads
      int s = it * 256 + tid;
      int d = s >> 3, p = s & 7;
      dma16(Vz + (size_t)b * DKD * SL + (size_t)d * SL + kb + p * 8,
            (char*)Vs + (it * 256 + wave * 64) * 16);
    }
    __syncthreads();

    // S = Q K^T : 4 key-tiles
    f32x4 s4[4];
    #pragma unroll
    for (int nt = 0; nt < 4; ++nt) {
      f32x4 c = f32x4{0.f,0.f,0.f,0.f};
      const int j = nt * 16 + mm;
      #pragma unroll
      for (int cc = 0; cc < 4; ++cc) {
        const int pp = (cc * 4 + quad) ^ mm;
        bf16x8 kf = *(const bf16x8*)(Ks + j * 128 + pp * 8);
        c = mfma16(aQ[cc], kf, c);
      }
      s4[nt] = c;
    }

    float alpha[4];
    #pragma unroll
    for (int reg = 0; reg < 4; ++reg) {
      const int jl = min(irow0 + reg + 1, len);
      float v0 = (kb + mm      < jl) ? s4[0][reg] : -__builtin_inff();
      float v1 = (kb + 16 + mm < jl) ? s4[1][reg] : -__builtin_inff();
      float v2 = (kb + 32 + mm < jl) ? s4[2][reg] : -__builtin_inff();
      float v3 = (kb + 48 + mm < jl) ? s4[3][reg] : -__builtin_inff();
      float mx = fmaxf(fmaxf(v0, v1), fmaxf(v2, v3));
      #pragma unroll
      for (int xm = 1; xm < 16; xm <<= 1) mx = fmaxf(mx, __shfl_xor(mx, xm));
      const float mn = fmaxf(mr[reg], mx);
      alpha[reg] = __builtin_amdgcn_exp2f(mr[reg] - mn);
      const float p0 = __builtin_amdgcn_exp2f(v0 - mn);
      const float p1 = __builtin_amdgcn_exp2f(v1 - mn);
      const float p2 = __builtin_amdgcn_exp2f(v2 - mn);
      const float p3 = __builtin_amdgcn_exp2f(v3 - mn);
      float sm = (p0 + p1) + (p2 + p3);
      #pragma unroll
      for (int xm = 1; xm < 16; xm <<= 1) sm += __shfl_xor(sm, xm);
      lr[reg] = lr[reg] * alpha[reg] + sm;
      mr[reg] = mn;
      const int prow = quad * 4 + reg;
      Ps[wave][prow * 72 + mm]      = f2bf(p0);
      Ps[wave][prow * 72 + 16 + mm] = f2bf(p1);
      Ps[wave][prow * 72 + 32 + mm] = f2bf(p2);
      Ps[wave][prow * 72 + 48 + mm] = f2bf(p3);
    }
    #pragma unroll
    for (int nt = 0; nt < 8; ++nt) {
      f32x4 a = acc[nt];
      a[0] *= alpha[0]; a[1] *= alpha[1]; a[2] *= alpha[2]; a[3] *= alpha[3];
      acc[nt] = a;
    }
    __asm__ volatile("s_waitcnt lgkmcnt(0)" ::: "memory");  // P writes -> reads
    bf16x8 aP[2];
    #pragma unroll
    for (int ks = 0; ks < 2; ++ks)
      aP[ks] = *(const bf16x8*)(&Ps[wave][mm * 72 + ks * 32 + quad * 8]);
    #pragma unroll
    for (int ks = 0; ks < 2; ++ks)
      #pragma unroll
      for (int nt = 0; nt < 8; ++nt) {
        const int pp = (ks * 4 + quad) ^ (mm & 7);
        bf16x8 vf = *(const bf16x8*)(Vs + (nt * 16 + mm) * 64 + pp * 8);
        acc[nt] = mfma16(aP[ks], vf, acc[nt]);
      }
  }

  #pragma unroll
  for (int reg = 0; reg < 4; ++reg) {
    const float rl = 1.0f / lr[reg];
    const size_t base = ((size_t)b * SL + irow0 + reg) * DKD + mm;
    #pragma unroll
    for (int nt = 0; nt < 8; ++nt)
      out[base + nt * 16] = acc[nt][reg] * rl;
  }
}

// ---------------------------------------------------------------------------
extern "C" void kernel_launch(void* const* d_in, const int* in_sizes, int n_in,
                              void* d_out, int out_size, void* d_ws, size_t ws_size,
                              hipStream_t stream) {
  const float* x    = (const float*)d_in[0];
  const float* ctx  = (const float*)d_in[1];
  const int*   lens = (const int*)d_in[2];
  const float* Wq   = (const float*)d_in[3];
  const float* Wk   = (const float*)d_in[4];
  const float* Wv   = (const float*)d_in[5];
  float* out = (float*)d_out;

  const size_t QKV = (size_t)NB * SL * DKD * sizeof(unsigned short); // 8 MiB each
  const size_t WTSZ = (size_t)3 * 16 * 128 * 8 * 8 * sizeof(unsigned short); // 768 KiB
  if (ws_size < 3 * QKV + WTSZ) return;
  unsigned short* Qws = (unsigned short*)d_ws;
  unsigned short* Kzs = (unsigned short*)((char*)d_ws + QKV);
  unsigned short* Vzs = (unsigned short*)((char*)d_ws + 2 * QKV);
  unsigned short* Wt  = (unsigned short*)((char*)d_ws + 3 * QKV);

  prep_w <<<dim3(192), 256, 0, stream>>>(Wq, Wk, Wv, Wt);
  proj_qk<<<dim3(NB * SL / 64), 256, 0, stream>>>(ctx, Wt, lens, Qws, Kzs);
  proj_v <<<dim3(NB * SL / 64), 256, 0, stream>>>(x, Wt, Vzs);
  attn   <<<dim3(SL / 64, NB), 256, 0, stream>>>(Qws, Kzs, Vzs, lens, out);
}

// Round 3
// 430.458 us; speedup vs baseline: 1.2069x; 1.0495x over previous
//
#include <hip/hip_runtime.h>

#define DEV __device__ __forceinline__

typedef __attribute__((ext_vector_type(4))) float f32x4;
typedef __attribute__((ext_vector_type(4))) unsigned short u16x4;
typedef __attribute__((ext_vector_type(8))) __bf16 bf16x8;

constexpr int NB = 16, SL = 2048, EM = 1024, DKD = 128;

DEV unsigned short f2bf(float f) {           // fp32 -> bf16 RNE
  unsigned int u = __float_as_uint(f);
  u += 0x7FFFu + ((u >> 16) & 1u);
  return (unsigned short)(u >> 16);
}

DEV f32x4 mfma16(bf16x8 a, bf16x8 b, f32x4 c) {
  return __builtin_amdgcn_mfma_f32_16x16x32_bf16(a, b, c, 0, 0, 0);
}

// async global->LDS DMA, 16B per lane; lds dst = wave-uniform base + lane*16
DEV void dma16(const void* g, void* l) {
  __builtin_amdgcn_global_load_lds(
      (const __attribute__((address_space(1))) unsigned int*)g,
      (__attribute__((address_space(3))) unsigned int*)l, 16, 0, 0);
}

DEV bf16x8 cvt8(f32x4 a, f32x4 b) {
  bf16x8 r;
  r[0] = (__bf16)a[0]; r[1] = (__bf16)a[1]; r[2] = (__bf16)a[2]; r[3] = (__bf16)a[3];
  r[4] = (__bf16)b[0]; r[5] = (__bf16)b[1]; r[6] = (__bf16)b[2]; r[7] = (__bf16)b[3];
  return r;
}

// ---------------------------------------------------------------------------
// prep_w: Wq/Wk/Wv fp32 [1024][128] -> bf16, tiled+swizzled, DMA-ready.
// Chunk t = ((m*16 + kc)*128 + n)*8 + p holds W_m[k = kc*64 + (p^(n&7))*8 + e][n].
// LDS-staged: coalesced reads + coalesced writes.
// ---------------------------------------------------------------------------
__global__ __launch_bounds__(256) void prep_w(
    const float* __restrict__ Wq, const float* __restrict__ Wk,
    const float* __restrict__ Wv, unsigned short* __restrict__ Wt)
{
  __shared__ unsigned short T[64 * 128];     // [kk][n] bf16
  const int tid = threadIdx.x;
  const int m = blockIdx.x >> 4, kc = blockIdx.x & 15;   // 48 blocks
  const float* W = (m == 0) ? Wq : ((m == 1) ? Wk : Wv);
  #pragma unroll
  for (int it = 0; it < 8; ++it) {
    int idx = it * 256 + tid;                // 2048 f32x4 chunks
    int kk = idx >> 5, n4 = (idx & 31) * 4;
    f32x4 w4 = *(const f32x4*)(W + (size_t)(kc * 64 + kk) * DKD + n4);
    *(u16x4*)&T[kk * 128 + n4] =
        u16x4{ f2bf(w4[0]), f2bf(w4[1]), f2bf(w4[2]), f2bf(w4[3]) };
  }
  __syncthreads();
  #pragma unroll
  for (int it = 0; it < 4; ++it) {
    int idx = it * 256 + tid;                // 1024 out chunks, p fastest
    int p = idx & 7, n = idx >> 3;
    int c = p ^ (n & 7);
    unsigned short v[8];
    #pragma unroll
    for (int e = 0; e < 8; ++e) v[e] = T[(c * 8 + e) * 128 + n];
    size_t t = ((size_t)(m * 16 + kc) * 128 + n) * 8 + p;
    *(u16x4*)(Wt + t * 8)     = u16x4{v[0], v[1], v[2], v[3]};
    *(u16x4*)(Wt + t * 8 + 4) = u16x4{v[4], v[5], v[6], v[7]};
  }
}

// ---------------------------------------------------------------------------
// proj_qk: Q,K = ctx @ {Wq,Wk}. M-tile 64 (grid 512), N = 256 (Q|K).
// Pipelined: dbuf weight LDS via DMA; A prefetched to regs one iter ahead.
// One barrier per iteration. Q written plain (masked+scaled); K swizzled.
// ---------------------------------------------------------------------------
__global__ __launch_bounds__(256, 2) void proj_qk(
    const float* __restrict__ ctx, const unsigned short* __restrict__ Wt,
    const int* __restrict__ lens, unsigned short* __restrict__ Qo,
    unsigned short* __restrict__ Kz)
{
  __shared__ unsigned short Ws[2][256 * 64];
  const int tid = threadIdx.x;
  const int wave = tid >> 6, lane = tid & 63;
  const int quad = lane >> 4, mm = lane & 15;
  const int rb = blockIdx.x * 64;

  f32x4 acc[4][4];
  #pragma unroll
  for (int i = 0; i < 4; ++i)
    #pragma unroll
    for (int j = 0; j < 4; ++j) acc[i][j] = f32x4{0.f, 0.f, 0.f, 0.f};

  f32x4 An[4][2][2];
  // prologue: DMA(0) -> buf0, A(0) -> regs
  #pragma unroll
  for (int it = 0; it < 8; ++it) {
    int s = it * 256 + tid;
    int mtx = s >> 10, sl = s & 1023;
    dma16(Wt + ((size_t)mtx * 16384 + sl) * 8,
          (char*)Ws[0] + (it * 256 + wave * 64) * 16);
  }
  #pragma unroll
  for (int rt = 0; rt < 4; ++rt)
    #pragma unroll
    for (int ks = 0; ks < 2; ++ks) {
      const float* ap = ctx + (size_t)(rb + rt * 16 + mm) * EM + ks * 32 + quad * 8;
      An[rt][ks][0] = *(const f32x4*)ap;
      An[rt][ks][1] = *(const f32x4*)(ap + 4);
    }

  #pragma unroll 1
  for (int kc = 0; kc < 16; ++kc) {
    bf16x8 af[4][2];
    #pragma unroll
    for (int rt = 0; rt < 4; ++rt)
      #pragma unroll
      for (int ks = 0; ks < 2; ++ks) af[rt][ks] = cvt8(An[rt][ks][0], An[rt][ks][1]);
    __syncthreads();                        // drains DMA(kc) (issued last iter)
    if (kc < 15) {                          // issue next iteration's memory
      #pragma unroll
      for (int it = 0; it < 8; ++it) {
        int s = it * 256 + tid;
        int mtx = s >> 10, sl = s & 1023;
        dma16(Wt + ((size_t)mtx * 16384 + (kc + 1) * 1024 + sl) * 8,
              (char*)Ws[(kc + 1) & 1] + (it * 256 + wave * 64) * 16);
      }
      #pragma unroll
      for (int rt = 0; rt < 4; ++rt)
        #pragma unroll
        for (int ks = 0; ks < 2; ++ks) {
          const float* ap = ctx + (size_t)(rb + rt * 16 + mm) * EM
                          + (kc + 1) * 64 + ks * 32 + quad * 8;
          An[rt][ks][0] = *(const f32x4*)ap;
          An[rt][ks][1] = *(const f32x4*)(ap + 4);
        }
    }
    const unsigned short* wb = Ws[kc & 1];
    #pragma unroll
    for (int lo = 0; lo < 4; ++lo) {
      const int nrow = (wave * 4 + lo) * 16 + mm;
      #pragma unroll
      for (int ks = 0; ks < 2; ++ks) {
        const int pp = (ks * 4 + quad) ^ (mm & 7);
        bf16x8 bf = *(const bf16x8*)(wb + nrow * 64 + pp * 8);
        #pragma unroll
        for (int rt = 0; rt < 4; ++rt)
          acc[rt][lo] = mfma16(af[rt][ks], bf, acc[rt][lo]);
      }
    }
  }
  const int len = lens[blockIdx.x >> 5];
  const float SCALE = 1.4426950408889634f * 0.08838834764831845f; // log2e/sqrt(128)
  #pragma unroll
  for (int rt = 0; rt < 4; ++rt)
    #pragma unroll
    for (int lo = 0; lo < 4; ++lo) {
      const int ctg = wave * 4 + lo;
      #pragma unroll
      for (int reg = 0; reg < 4; ++reg) {
        const int row = rb + rt * 16 + quad * 4 + reg;
        const int j = row & (SL - 1);
        const float val = acc[rt][lo][reg];
        if (ctg < 8) {
          const int d = ctg * 16 + mm;
          Qo[(size_t)row * DKD + d] = f2bf(val * ((j < len) ? SCALE : 0.f));
        } else {
          const int d = (ctg - 8) * 16 + mm;
          Kz[(size_t)row * DKD + (((d >> 3) ^ (j & 15)) * 8) + (d & 7)] = f2bf(val);
        }
      }
    }
}

// ---------------------------------------------------------------------------
// proj_v: V = x @ Wv, pipelined like proj_qk; output transposed+window-swizzled
// Vz[b][d][j-windows].
// ---------------------------------------------------------------------------
__global__ __launch_bounds__(256, 2) void proj_v(
    const float* __restrict__ x, const unsigned short* __restrict__ Wt,
    unsigned short* __restrict__ Vz)
{
  __shared__ unsigned short Ws[2][128 * 64];
  const int tid = threadIdx.x;
  const int wave = tid >> 6, lane = tid & 63;
  const int quad = lane >> 4, mm = lane & 15;
  const int rb = blockIdx.x * 64;

  f32x4 acc[4][2];
  #pragma unroll
  for (int i = 0; i < 4; ++i) { acc[i][0] = f32x4{0.f,0.f,0.f,0.f}; acc[i][1] = f32x4{0.f,0.f,0.f,0.f}; }

  f32x4 An[4][2][2];
  #pragma unroll
  for (int it = 0; it < 4; ++it) {
    int s = it * 256 + tid;
    dma16(Wt + ((size_t)2 * 16384 + s) * 8,
          (char*)Ws[0] + (it * 256 + wave * 64) * 16);
  }
  #pragma unroll
  for (int rt = 0; rt < 4; ++rt)
    #pragma unroll
    for (int ks = 0; ks < 2; ++ks) {
      const float* ap = x + (size_t)(rb + rt * 16 + mm) * EM + ks * 32 + quad * 8;
      An[rt][ks][0] = *(const f32x4*)ap;
      An[rt][ks][1] = *(const f32x4*)(ap + 4);
    }

  #pragma unroll 1
  for (int kc = 0; kc < 16; ++kc) {
    bf16x8 af[4][2];
    #pragma unroll
    for (int rt = 0; rt < 4; ++rt)
      #pragma unroll
      for (int ks = 0; ks < 2; ++ks) af[rt][ks] = cvt8(An[rt][ks][0], An[rt][ks][1]);
    __syncthreads();
    if (kc < 15) {
      #pragma unroll
      for (int it = 0; it < 4; ++it) {
        int s = it * 256 + tid;
        dma16(Wt + ((size_t)2 * 16384 + (kc + 1) * 1024 + s) * 8,
              (char*)Ws[(kc + 1) & 1] + (it * 256 + wave * 64) * 16);
      }
      #pragma unroll
      for (int rt = 0; rt < 4; ++rt)
        #pragma unroll
        for (int ks = 0; ks < 2; ++ks) {
          const float* ap = x + (size_t)(rb + rt * 16 + mm) * EM
                          + (kc + 1) * 64 + ks * 32 + quad * 8;
          An[rt][ks][0] = *(const f32x4*)ap;
          An[rt][ks][1] = *(const f32x4*)(ap + 4);
        }
    }
    const unsigned short* wb = Ws[kc & 1];
    #pragma unroll
    for (int lo = 0; lo < 2; ++lo) {
      const int nrow = (wave * 2 + lo) * 16 + mm;
      #pragma unroll
      for (int ks = 0; ks < 2; ++ks) {
        const int pp = (ks * 4 + quad) ^ (mm & 7);
        bf16x8 bf = *(const bf16x8*)(wb + nrow * 64 + pp * 8);
        #pragma unroll
        for (int rt = 0; rt < 4; ++rt)
          acc[rt][lo] = mfma16(af[rt][ks], bf, acc[rt][lo]);
      }
    }
  }
  #pragma unroll
  for (int rt = 0; rt < 4; ++rt)
    #pragma unroll
    for (int lo = 0; lo < 2; ++lo) {
      const int d = (wave * 2 + lo) * 16 + mm;
      const int row0 = rb + rt * 16 + quad * 4;
      const int b = row0 >> 11, j0 = row0 & (SL - 1);
      u16x4 pk = u16x4{ f2bf(acc[rt][lo][0]), f2bf(acc[rt][lo][1]),
                        f2bf(acc[rt][lo][2]), f2bf(acc[rt][lo][3]) };
      size_t off = (size_t)b * DKD * SL + (size_t)d * SL + (j0 & ~63)
                 + ((((j0 >> 3) & 7) ^ (d & 7)) * 8) + (j0 & 7);
      *(u16x4*)(Vz + off) = pk;
    }
}

// ---------------------------------------------------------------------------
// attn: flash attention, 64 q-rows/block, pipelined 64-key blocks (dbuf DMA).
// Fully-padded query blocks (qb >= len) short-circuit to mean(V[0..len)).
// ---------------------------------------------------------------------------
__global__ __launch_bounds__(256, 2) void attn(
    const unsigned short* __restrict__ Qw, const unsigned short* __restrict__ Kz,
    const unsigned short* __restrict__ Vz, const int* __restrict__ lens,
    float* __restrict__ out)
{
  __shared__ unsigned short Ks[2][64 * 128];   // [j][16 chunks x 8], swz c^(j&15)
  __shared__ unsigned short Vs[2][128 * 64];   // [d][8 chunks x 8],  swz c^(d&7)
  __shared__ unsigned short Ps[4][16 * 72];    // per-wave P [q][j+pad8]
  __shared__ float mv[128];
  const int tid = threadIdx.x;
  const int wave = tid >> 6, lane = tid & 63;
  const int quad = lane >> 4, mm = lane & 15;
  const int b = blockIdx.y;
  const int qb = ((int)gridDim.x - 1 - (int)blockIdx.x) * 64;  // heavy blocks first
  const int len = lens[b];

  if (qb >= len) {
    // ---- mean-V path: every row in this block averages V[0..len) ----
    const int half = tid >> 7, d = tid & 127, d7 = d & 7;
    const unsigned short* vbase = Vz + (size_t)b * DKD * SL + (size_t)d * SL;
    float sum = 0.f;
    for (int j0 = half * 64; j0 < len; j0 += 128) {
      #pragma unroll
      for (int cc = 0; cc < 8; ++cc) {
        const int jstart = j0 + cc * 8;
        if (jstart >= len) break;
        const unsigned short* p = vbase + j0 + ((cc ^ d7) * 8);
        if (jstart + 8 <= len) {
          bf16x8 v = *(const bf16x8*)p;
          sum += (float)v[0] + (float)v[1] + (float)v[2] + (float)v[3]
               + (float)v[4] + (float)v[5] + (float)v[6] + (float)v[7];
        } else {
          for (int r = 0; r < 8; ++r)
            if (jstart + r < len) sum += (float)*(const __bf16*)(p + r);
        }
      }
    }
    if (half == 0) mv[d] = sum;
    __syncthreads();
    if (half == 1) mv[d] += sum;
    __syncthreads();
    const float val = mv[d] / (float)len;
    #pragma unroll 1
    for (int it = 0; it < 32; ++it) {
      const int row = qb + half + it * 2;
      out[((size_t)b * SL + row) * DKD + d] = val;
    }
    return;
  }

  const int kend = min(qb + 64, len);
  const int nblk = (kend + 63) >> 6;
  const int irow0 = qb + wave * 16 + quad * 4;

  bf16x8 aQ[4];
  {
    const unsigned short* qbase =
        Qw + (size_t)(b * SL + qb + wave * 16 + mm) * DKD + quad * 8;
    #pragma unroll
    for (int cc = 0; cc < 4; ++cc) aQ[cc] = *(const bf16x8*)(qbase + cc * 32);
  }
  float mr[4], lr[4];
  #pragma unroll
  for (int r = 0; r < 4; ++r) { mr[r] = -__builtin_inff(); lr[r] = 0.f; }
  f32x4 acc[8];
  #pragma unroll
  for (int i = 0; i < 8; ++i) acc[i] = f32x4{0.f,0.f,0.f,0.f};

  // prologue DMA: block 0 -> buf 0
  #pragma unroll
  for (int it = 0; it < 4; ++it) {
    int s = it * 256 + tid;
    dma16(Kz + (size_t)(b * SL) * DKD + (size_t)s * 8,
          (char*)Ks[0] + (it * 256 + wave * 64) * 16);
  }
  #pragma unroll
  for (int it = 0; it < 4; ++it) {
    int s = it * 256 + tid;
    int d = s >> 3, p = s & 7;
    dma16(Vz + (size_t)b * DKD * SL + (size_t)d * SL + p * 8,
          (char*)Vs[0] + (it * 256 + wave * 64) * 16);
  }

  #pragma unroll 1
  for (int blk = 0; blk < nblk; ++blk) {
    const int kb = blk * 64;
    __syncthreads();                       // drains DMA(blk)
    if (blk + 1 < nblk) {                  // issue next block's DMA
      const int kb1 = kb + 64;
      const int nb = (blk + 1) & 1;
      #pragma unroll
      for (int it = 0; it < 4; ++it) {
        int s = it * 256 + tid;
        dma16(Kz + (size_t)(b * SL + kb1) * DKD + (size_t)s * 8,
              (char*)Ks[nb] + (it * 256 + wave * 64) * 16);
      }
      #pragma unroll
      for (int it = 0; it < 4; ++it) {
        int s = it * 256 + tid;
        int d = s >> 3, p = s & 7;
        dma16(Vz + (size_t)b * DKD * SL + (size_t)d * SL + kb1 + p * 8,
              (char*)Vs[nb] + (it * 256 + wave * 64) * 16);
      }
    }
    const unsigned short* kbuf = Ks[blk & 1];
    const unsigned short* vbuf = Vs[blk & 1];

    // S = Q K^T : 4 key-tiles
    f32x4 s4[4];
    #pragma unroll
    for (int nt = 0; nt < 4; ++nt) {
      f32x4 c = f32x4{0.f,0.f,0.f,0.f};
      const int j = nt * 16 + mm;
      #pragma unroll
      for (int cc = 0; cc < 4; ++cc) {
        const int pp = (cc * 4 + quad) ^ mm;
        bf16x8 kf = *(const bf16x8*)(kbuf + j * 128 + pp * 8);
        c = mfma16(aQ[cc], kf, c);
      }
      s4[nt] = c;
    }

    float alpha[4];
    #pragma unroll
    for (int reg = 0; reg < 4; ++reg) {
      const int jl = min(irow0 + reg + 1, len);
      float v0 = (kb + mm      < jl) ? s4[0][reg] : -__builtin_inff();
      float v1 = (kb + 16 + mm < jl) ? s4[1][reg] : -__builtin_inff();
      float v2 = (kb + 32 + mm < jl) ? s4[2][reg] : -__builtin_inff();
      float v3 = (kb + 48 + mm < jl) ? s4[3][reg] : -__builtin_inff();
      float mx = fmaxf(fmaxf(v0, v1), fmaxf(v2, v3));
      #pragma unroll
      for (int xm = 1; xm < 16; xm <<= 1) mx = fmaxf(mx, __shfl_xor(mx, xm));
      const float mn = fmaxf(mr[reg], mx);
      alpha[reg] = __builtin_amdgcn_exp2f(mr[reg] - mn);
      const float p0 = __builtin_amdgcn_exp2f(v0 - mn);
      const float p1 = __builtin_amdgcn_exp2f(v1 - mn);
      const float p2 = __builtin_amdgcn_exp2f(v2 - mn);
      const float p3 = __builtin_amdgcn_exp2f(v3 - mn);
      float sm = (p0 + p1) + (p2 + p3);
      #pragma unroll
      for (int xm = 1; xm < 16; xm <<= 1) sm += __shfl_xor(sm, xm);
      lr[reg] = lr[reg] * alpha[reg] + sm;
      mr[reg] = mn;
      const int prow = quad * 4 + reg;
      Ps[wave][prow * 72 + mm]      = f2bf(p0);
      Ps[wave][prow * 72 + 16 + mm] = f2bf(p1);
      Ps[wave][prow * 72 + 32 + mm] = f2bf(p2);
      Ps[wave][prow * 72 + 48 + mm] = f2bf(p3);
    }
    #pragma unroll
    for (int nt = 0; nt < 8; ++nt) {
      f32x4 a = acc[nt];
      a[0] *= alpha[0]; a[1] *= alpha[1]; a[2] *= alpha[2]; a[3] *= alpha[3];
      acc[nt] = a;
    }
    __asm__ volatile("s_waitcnt lgkmcnt(0)" ::: "memory");  // P writes -> reads
    bf16x8 aP[2];
    #pragma unroll
    for (int ks = 0; ks < 2; ++ks)
      aP[ks] = *(const bf16x8*)(&Ps[wave][mm * 72 + ks * 32 + quad * 8]);
    #pragma unroll
    for (int ks = 0; ks < 2; ++ks)
      #pragma unroll
      for (int nt = 0; nt < 8; ++nt) {
        const int pp = (ks * 4 + quad) ^ (mm & 7);
        bf16x8 vf = *(const bf16x8*)(vbuf + (nt * 16 + mm) * 64 + pp * 8);
        acc[nt] = mfma16(aP[ks], vf, acc[nt]);
      }
  }

  #pragma unroll
  for (int reg = 0; reg < 4; ++reg) {
    const float rl = 1.0f / lr[reg];
    const size_t base = ((size_t)b * SL + irow0 + reg) * DKD + mm;
    #pragma unroll
    for (int nt = 0; nt < 8; ++nt)
      out[base + nt * 16] = acc[nt][reg] * rl;
  }
}

// ---------------------------------------------------------------------------
extern "C" void kernel_launch(void* const* d_in, const int* in_sizes, int n_in,
                              void* d_out, int out_size, void* d_ws, size_t ws_size,
                              hipStream_t stream) {
  const float* x    = (const float*)d_in[0];
  const float* ctx  = (const float*)d_in[1];
  const int*   lens = (const int*)d_in[2];
  const float* Wq   = (const float*)d_in[3];
  const float* Wk   = (const float*)d_in[4];
  const float* Wv   = (const float*)d_in[5];
  float* out = (float*)d_out;

  const size_t QKV = (size_t)NB * SL * DKD * sizeof(unsigned short); // 8 MiB each
  const size_t WTSZ = (size_t)3 * 16 * 128 * 8 * 8 * sizeof(unsigned short); // 768 KiB
  if (ws_size < 3 * QKV + WTSZ) return;
  unsigned short* Qws = (unsigned short*)d_ws;
  unsigned short* Kzs = (unsigned short*)((char*)d_ws + QKV);
  unsigned short* Vzs = (unsigned short*)((char*)d_ws + 2 * QKV);
  unsigned short* Wt  = (unsigned short*)((char*)d_ws + 3 * QKV);

  prep_w <<<dim3(48), 256, 0, stream>>>(Wq, Wk, Wv, Wt);
  proj_qk<<<dim3(NB * SL / 64), 256, 0, stream>>>(ctx, Wt, lens, Qws, Kzs);
  proj_v <<<dim3(NB * SL / 64), 256, 0, stream>>>(x, Wt, Vzs);
  attn   <<<dim3(SL / 64, NB), 256, 0, stream>>>(Qws, Kzs, Vzs, lens, out);
}